// Round 1
// baseline (542.492 us; speedup 1.0000x reference)
//
#include <hip/hip_runtime.h>
#include <hip/hip_bf16.h>
#include <cstdint>
#include <cstddef>

#define TOK 8192
#define DIM 1024
#define FF  2048
#define NE  8

typedef __attribute__((ext_vector_type(8))) short short8;
typedef __attribute__((ext_vector_type(4))) float f32x4;

__device__ inline void gload_lds16(const void* g, void* l) {
  __builtin_amdgcn_global_load_lds(
      (const __attribute__((address_space(1))) unsigned int*)g,
      (__attribute__((address_space(3))) unsigned int*)l, 16, 0, 0);
}

__device__ inline unsigned short f2bf(float f) {
  unsigned int u = __float_as_uint(f);
  u += 0x7fffu + ((u >> 16) & 1u);   // RNE
  return (unsigned short)(u >> 16);
}
__device__ inline float bf2f(unsigned short u) {
  return __uint_as_float(((unsigned int)u) << 16);
}

// ---------------- weight fp32 -> bf16 ----------------
__global__ __launch_bounds__(256) void convert_kernel(
    const float* __restrict__ src, unsigned short* __restrict__ dst, int n) {
  const int stride = gridDim.x * blockDim.x * 4;
  for (int i = (blockIdx.x * blockDim.x + threadIdx.x) * 4; i < n; i += stride) {
    const float4 v = *reinterpret_cast<const float4*>(src + i);
    ushort4 o;
    o.x = f2bf(v.x); o.y = f2bf(v.y); o.z = f2bf(v.z); o.w = f2bf(v.w);
    *reinterpret_cast<ushort4*>(dst + i) = o;
  }
}

// ---------------- gating: logits, top-2, assign ----------------
__global__ __launch_bounds__(256) void gate_kernel(
    const float* __restrict__ x, const float* __restrict__ Wg,
    const float* __restrict__ bg, int* __restrict__ assign,
    int* __restrict__ counts) {
  const int token = blockIdx.x * 4 + (threadIdx.x >> 6);
  const int lane = threadIdx.x & 63;
  if (token >= TOK) return;
  const float* xr = x + (size_t)token * DIM;
  float acc[NE];
#pragma unroll
  for (int e = 0; e < NE; ++e) acc[e] = 0.f;
  for (int i = lane; i < DIM; i += 64) {
    const float xv = xr[i];
#pragma unroll
    for (int e = 0; e < NE; ++e) acc[e] += xv * Wg[e * DIM + i];
  }
#pragma unroll
  for (int e = 0; e < NE; ++e) {
    float v = acc[e];
#pragma unroll
    for (int s = 32; s; s >>= 1) v += __shfl_xor(v, s);
    acc[e] = v + bg[e];
  }
  if (lane == 0) {
    float v1 = -INFINITY, v2 = -INFINITY; int i1 = 0, i2 = 0;
#pragma unroll
    for (int e = 0; e < NE; ++e) {
      const float v = acc[e];
      if (v > v1)      { v2 = v1; i2 = i1; v1 = v; i1 = e; }
      else if (v > v2) { v2 = v; i2 = e; }
    }
    const int a = (i1 > i2) ? i1 : i2;   // max(top2 indices); w == 1.0
    assign[token] = a;
    atomicAdd(&counts[a], 1);
  }
}

// ---------------- prefix scan of counts ----------------
__global__ void scan_kernel(int* __restrict__ ctrl) {
  // ctrl: [0..7]=counts, [8..15]=cursor, [16..24]=offsets
  if (threadIdx.x == 0 && blockIdx.x == 0) {
    int s = 0;
#pragma unroll
    for (int e = 0; e < NE; ++e) { ctrl[16 + e] = s; s += ctrl[e]; }
    ctrl[24] = s;
  }
}

// ---------------- gather tokens into expert-contiguous bf16 rows ----------------
__global__ __launch_bounds__(256) void gather_kernel(
    const float* __restrict__ x, const int* __restrict__ assign,
    const int* __restrict__ offsets, int* __restrict__ cursor,
    int* __restrict__ ridx, unsigned short* __restrict__ Xb) {
  const int token = blockIdx.x;
  __shared__ int srow;
  if (threadIdx.x == 0) {
    const int a = assign[token];
    const int pos = atomicAdd(&cursor[a], 1);
    const int row = offsets[a] + pos;
    ridx[row] = token;
    srow = row;
  }
  __syncthreads();
  const int row = srow;
  const int j = threadIdx.x * 4;
  const float4 v = *reinterpret_cast<const float4*>(x + (size_t)token * DIM + j);
  ushort4 o;
  o.x = f2bf(v.x); o.y = f2bf(v.y); o.z = f2bf(v.z); o.w = f2bf(v.w);
  *reinterpret_cast<ushort4*>(Xb + (size_t)row * DIM + j) = o;
}

// ---------------- grouped GEMM1: H = Xb @ W1e^T + b1  (bf16 out) ----------------
__global__ __launch_bounds__(256) void gemm1_kernel(
    const unsigned short* __restrict__ Xb, const unsigned short* __restrict__ W1b,
    const float* __restrict__ b1, const int* __restrict__ offsets,
    unsigned short* __restrict__ Hb) {
  const int e = blockIdx.z;
  const int base = offsets[e];
  const int count = offsets[e + 1] - base;
  const int m_tile = blockIdx.y;
  if (m_tile * 128 >= count) return;
  const int n0 = blockIdx.x * 128;
  constexpr int K = DIM;
  __shared__ unsigned short As[128 * 64];
  __shared__ unsigned short Bs[128 * 64];
  const int tid = threadIdx.x;
  const int wave = tid >> 6, lane = tid & 63;
  const int wr = wave >> 1, wc = wave & 1;
  f32x4 acc[4][4] = {};
  const unsigned short* Ag = Xb + (size_t)(base + m_tile * 128) * K;
  const unsigned short* Bg = W1b + ((size_t)e * FF + n0) * K;
  const int arow = lane >> 3;
  const int acol = (lane & 7) * 8;
  for (int k0 = 0; k0 < K; k0 += 64) {
    __syncthreads();
#pragma unroll
    for (int it = 0; it < 4; ++it) {
      const int c = it * 4 + wave;          // wave-uniform chunk id
      const int r = c * 8 + arow;
      gload_lds16(Ag + (size_t)r * K + k0 + acol, &As[c * 512]);
      gload_lds16(Bg + (size_t)r * K + k0 + acol, &Bs[c * 512]);
    }
    __syncthreads();
#pragma unroll
    for (int kk = 0; kk < 64; kk += 32) {
      short8 a[4], b[4];
#pragma unroll
      for (int i = 0; i < 4; ++i)
        a[i] = *reinterpret_cast<const short8*>(
            &As[(wr * 64 + i * 16 + (lane & 15)) * 64 + kk + (lane >> 4) * 8]);
#pragma unroll
      for (int j = 0; j < 4; ++j)
        b[j] = *reinterpret_cast<const short8*>(
            &Bs[(wc * 64 + j * 16 + (lane & 15)) * 64 + kk + (lane >> 4) * 8]);
#pragma unroll
      for (int i = 0; i < 4; ++i)
#pragma unroll
        for (int j = 0; j < 4; ++j)
          acc[i][j] = __builtin_amdgcn_mfma_f32_16x16x32_bf16(a[i], b[j], acc[i][j], 0, 0, 0);
    }
  }
  const float* b1e = b1 + (size_t)e * FF;
  const int rbase = m_tile * 128 + wr * 64 + (lane >> 4) * 4;
  const int cbase = n0 + wc * 64 + (lane & 15);
#pragma unroll
  for (int i = 0; i < 4; ++i) {
#pragma unroll
    for (int j = 0; j < 4; ++j) {
      const int col = cbase + j * 16;
      const float bias = b1e[col];
#pragma unroll
      for (int r = 0; r < 4; ++r) {
        const int lr = rbase + i * 16 + r;
        if (lr < count)
          Hb[(size_t)(base + lr) * FF + col] = f2bf(acc[i][j][r] + bias);
      }
    }
  }
}

// ---------------- LayerNorm + exact GELU, in place on Hb ----------------
__global__ __launch_bounds__(256) void ln_gelu_kernel(
    unsigned short* __restrict__ Hb, const float* __restrict__ ln_g,
    const float* __restrict__ ln_b, const int* __restrict__ offsets) {
  const int row = blockIdx.x;
  int e = 0;
#pragma unroll
  for (int i = 1; i < NE; ++i) e += (row >= offsets[i]) ? 1 : 0;
  unsigned short* h = Hb + (size_t)row * FF;
  const int tid = threadIdx.x;
  const int lane = tid & 63, wave = tid >> 6;
  float v[8];
  float sum = 0.f, sq = 0.f;
  short8 raw = *reinterpret_cast<const short8*>(h + tid * 8);
#pragma unroll
  for (int i = 0; i < 8; ++i) {
    v[i] = bf2f((unsigned short)raw[i]);
    sum += v[i]; sq += v[i] * v[i];
  }
#pragma unroll
  for (int s = 32; s; s >>= 1) { sum += __shfl_xor(sum, s); sq += __shfl_xor(sq, s); }
  __shared__ float red[8];
  if (lane == 0) { red[wave] = sum; red[wave + 4] = sq; }
  __syncthreads();
  sum = red[0] + red[1] + red[2] + red[3];
  sq  = red[4] + red[5] + red[6] + red[7];
  const float mu = sum * (1.f / FF);
  const float var = sq * (1.f / FF) - mu * mu;
  const float rstd = rsqrtf(var + 1e-5f);
  const float* ge = ln_g + (size_t)e * FF + tid * 8;
  const float* be = ln_b + (size_t)e * FF + tid * 8;
  short8 outv;
#pragma unroll
  for (int i = 0; i < 8; ++i) {
    const float t = (v[i] - mu) * rstd * ge[i] + be[i];
    const float g = 0.5f * t * (1.f + erff(t * 0.70710678118f));
    outv[i] = (short)f2bf(g);
  }
  *reinterpret_cast<short8*>(h + tid * 8) = outv;
}

// ---------------- grouped GEMM2: out[t] = (Hb @ W2e^T + b2)*se + x[t] ----------------
__global__ __launch_bounds__(256) void gemm2_kernel(
    const unsigned short* __restrict__ Hb, const unsigned short* __restrict__ W2b,
    const float* __restrict__ b2, const float* __restrict__ res_scale,
    const int* __restrict__ offsets, const int* __restrict__ ridx,
    const float* __restrict__ x, float* __restrict__ out) {
  const int e = blockIdx.z;
  const int base = offsets[e];
  const int count = offsets[e + 1] - base;
  const int m_tile = blockIdx.y;
  if (m_tile * 128 >= count) return;
  const int n0 = blockIdx.x * 128;
  constexpr int K = FF;
  __shared__ unsigned short As[128 * 64];
  __shared__ unsigned short Bs[128 * 64];
  const int tid = threadIdx.x;
  const int wave = tid >> 6, lane = tid & 63;
  const int wr = wave >> 1, wc = wave & 1;
  f32x4 acc[4][4] = {};
  const unsigned short* Ag = Hb + (size_t)(base + m_tile * 128) * K;
  const unsigned short* Bg = W2b + ((size_t)e * DIM + n0) * K;
  const int arow = lane >> 3;
  const int acol = (lane & 7) * 8;
  for (int k0 = 0; k0 < K; k0 += 64) {
    __syncthreads();
#pragma unroll
    for (int it = 0; it < 4; ++it) {
      const int c = it * 4 + wave;
      const int r = c * 8 + arow;
      gload_lds16(Ag + (size_t)r * K + k0 + acol, &As[c * 512]);
      gload_lds16(Bg + (size_t)r * K + k0 + acol, &Bs[c * 512]);
    }
    __syncthreads();
#pragma unroll
    for (int kk = 0; kk < 64; kk += 32) {
      short8 a[4], b[4];
#pragma unroll
      for (int i = 0; i < 4; ++i)
        a[i] = *reinterpret_cast<const short8*>(
            &As[(wr * 64 + i * 16 + (lane & 15)) * 64 + kk + (lane >> 4) * 8]);
#pragma unroll
      for (int j = 0; j < 4; ++j)
        b[j] = *reinterpret_cast<const short8*>(
            &Bs[(wc * 64 + j * 16 + (lane & 15)) * 64 + kk + (lane >> 4) * 8]);
#pragma unroll
      for (int i = 0; i < 4; ++i)
#pragma unroll
        for (int j = 0; j < 4; ++j)
          acc[i][j] = __builtin_amdgcn_mfma_f32_16x16x32_bf16(a[i], b[j], acc[i][j], 0, 0, 0);
    }
  }
  const float* b2e = b2 + (size_t)e * DIM;
  const float se = res_scale[e];
  const int rbase = m_tile * 128 + wr * 64 + (lane >> 4) * 4;
  const int cbase = n0 + wc * 64 + (lane & 15);
#pragma unroll
  for (int i = 0; i < 4; ++i) {
#pragma unroll
    for (int j = 0; j < 4; ++j) {
      const int col = cbase + j * 16;
      const float bias = b2e[col];
#pragma unroll
      for (int r = 0; r < 4; ++r) {
        const int lr = rbase + i * 16 + r;
        if (lr < count) {
          const int trow = ridx[base + lr];
          out[(size_t)trow * DIM + col] =
              (acc[i][j][r] + bias) * se + x[(size_t)trow * DIM + col];
        }
      }
    }
  }
}

extern "C" void kernel_launch(void* const* d_in, const int* in_sizes, int n_in,
                              void* d_out, int out_size, void* d_ws, size_t ws_size,
                              hipStream_t stream) {
  const float* x         = (const float*)d_in[0];
  const float* Wg        = (const float*)d_in[1];
  const float* bg        = (const float*)d_in[2];
  const float* W1        = (const float*)d_in[3];
  const float* b1        = (const float*)d_in[4];
  const float* ln_g      = (const float*)d_in[5];
  const float* ln_b      = (const float*)d_in[6];
  const float* W2        = (const float*)d_in[7];
  const float* b2        = (const float*)d_in[8];
  const float* res_scale = (const float*)d_in[9];
  float* out = (float*)d_out;

  char* ws = (char*)d_ws;
  // layout (bytes):
  //   W1b  @ 0          : 33,554,432  (E*F*D bf16)
  //   W2b  @ 33,554,432 : 33,554,432  (E*D*F bf16)
  //   Xb   @ 67,108,864 : 16,777,216  (T*D bf16, gathered)
  //   Hb   @ 83,886,080 : 33,554,432  (T*F bf16, gathered) + 512KB read-slack
  //   assign @ 117,964,800 : 32KB ; ridx @ 117,997,568 : 32KB ; ctrl @ 118,030,336
  unsigned short* W1b = (unsigned short*)(ws);
  unsigned short* W2b = (unsigned short*)(ws + 33554432);
  unsigned short* Xb  = (unsigned short*)(ws + 67108864);
  unsigned short* Hb  = (unsigned short*)(ws + 83886080);
  int* assign  = (int*)(ws + 117964800);
  int* ridx    = (int*)(ws + 117997568);
  int* ctrl    = (int*)(ws + 118030336);
  int* cursor  = ctrl + 8;
  int* offsets = ctrl + 16;

  hipMemsetAsync(ctrl, 0, 64, stream);  // counts + cursor
  convert_kernel<<<2048, 256, 0, stream>>>(W1, W1b, NE * FF * DIM);
  convert_kernel<<<2048, 256, 0, stream>>>(W2, W2b, NE * DIM * FF);
  gate_kernel<<<TOK / 4, 256, 0, stream>>>(x, Wg, bg, assign, ctrl);
  scan_kernel<<<1, 64, 0, stream>>>(ctrl);
  gather_kernel<<<TOK, 256, 0, stream>>>(x, assign, offsets, cursor, ridx, Xb);
  gemm1_kernel<<<dim3(16, 64, 8), 256, 0, stream>>>(Xb, W1b, b1, offsets, Hb);
  ln_gelu_kernel<<<TOK, 256, 0, stream>>>(Hb, ln_g, ln_b, offsets);
  gemm2_kernel<<<dim3(8, 64, 8), 256, 0, stream>>>(Hb, W2b, b2, res_scale, offsets, ridx, x, out);
}

// Round 2
// 502.830 us; speedup vs baseline: 1.0789x; 1.0789x over previous
//
#include <hip/hip_runtime.h>
#include <hip/hip_bf16.h>
#include <cstdint>
#include <cstddef>

#define TOK 8192
#define DIM 1024
#define FF  2048
#define NE  8
#define MAXTILES 72

typedef __attribute__((ext_vector_type(8))) short short8;
typedef __attribute__((ext_vector_type(4))) float f32x4;

__device__ inline void gload_lds16(const void* g, void* l) {
  __builtin_amdgcn_global_load_lds(
      (const __attribute__((address_space(1))) unsigned int*)g,
      (__attribute__((address_space(3))) unsigned int*)l, 16, 0, 0);
}

__device__ inline unsigned short f2bf(float f) {
  unsigned int u = __float_as_uint(f);
  u += 0x7fffu + ((u >> 16) & 1u);   // RNE
  return (unsigned short)(u >> 16);
}
__device__ inline float bf2f(unsigned short u) {
  return __uint_as_float(((unsigned int)u) << 16);
}

// ---------------- weight fp32 -> bf16 ----------------
__global__ __launch_bounds__(256) void convert_kernel(
    const float* __restrict__ src, unsigned short* __restrict__ dst, int n) {
  const int stride = gridDim.x * blockDim.x * 4;
  for (int i = (blockIdx.x * blockDim.x + threadIdx.x) * 4; i < n; i += stride) {
    const float4 v = *reinterpret_cast<const float4*>(src + i);
    ushort4 o;
    o.x = f2bf(v.x); o.y = f2bf(v.y); o.z = f2bf(v.z); o.w = f2bf(v.w);
    *reinterpret_cast<ushort4*>(dst + i) = o;
  }
}

// ---------------- gating: logits, top-2 (highest index wins), counts ----------------
__global__ __launch_bounds__(256) void gate_kernel(
    const float* __restrict__ x, const float* __restrict__ Wg,
    const float* __restrict__ bg, int* __restrict__ assign,
    int* __restrict__ counts) {
  const int token = blockIdx.x * 4 + (threadIdx.x >> 6);
  const int lane = threadIdx.x & 63;
  if (token >= TOK) return;
  const float* xr = x + (size_t)token * DIM;
  float acc[NE];
#pragma unroll
  for (int e = 0; e < NE; ++e) acc[e] = 0.f;
#pragma unroll
  for (int i0 = 0; i0 < DIM; i0 += 256) {
    const int i = i0 + lane * 4;
    const float4 xv = *reinterpret_cast<const float4*>(xr + i);
#pragma unroll
    for (int e = 0; e < NE; ++e) {
      const float4 wv = *reinterpret_cast<const float4*>(Wg + e * DIM + i);
      acc[e] += xv.x * wv.x + xv.y * wv.y + xv.z * wv.z + xv.w * wv.w;
    }
  }
#pragma unroll
  for (int e = 0; e < NE; ++e) {
    float v = acc[e];
#pragma unroll
    for (int s = 32; s; s >>= 1) v += __shfl_xor(v, s);
    acc[e] = v + bg[e];
  }
  if (lane == 0) {
    float v1 = -INFINITY, v2 = -INFINITY; int i1 = 0, i2 = 0;
#pragma unroll
    for (int e = 0; e < NE; ++e) {
      const float v = acc[e];
      if (v > v1)      { v2 = v1; i2 = i1; v1 = v; i1 = e; }
      else if (v > v2) { v2 = v; i2 = e; }
    }
    const int a = (i1 > i2) ? i1 : i2;   // max(top2 indices); softmax-sum weight == 1.0
    assign[token] = a;
    atomicAdd(&counts[a], 1);
  }
}

// ---------------- prefix scan + tile table ----------------
// ctrl: [0..7]=counts, [8..15]=cursor, [16..24]=offsets, [25]=ntiles,
//       [32..103]=tile_e, [128..199]=tile_m
__global__ void scan_kernel(int* __restrict__ ctrl) {
  if (threadIdx.x == 0 && blockIdx.x == 0) {
    int s = 0, nt = 0;
#pragma unroll
    for (int e = 0; e < NE; ++e) {
      ctrl[16 + e] = s;
      const int cnt = ctrl[e];
      for (int m = 0; m * 128 < cnt; ++m) {
        ctrl[32 + nt] = e;
        ctrl[128 + nt] = m;
        ++nt;
      }
      s += cnt;
    }
    ctrl[24] = s;
    ctrl[25] = nt;
  }
}

// ---------------- gather tokens into expert-contiguous bf16 rows ----------------
__global__ __launch_bounds__(256) void gather_kernel(
    const float* __restrict__ x, const int* __restrict__ assign,
    const int* __restrict__ offsets, int* __restrict__ cursor,
    int* __restrict__ ridx, unsigned short* __restrict__ Xb) {
  const int token = blockIdx.x;
  __shared__ int srow;
  if (threadIdx.x == 0) {
    const int a = assign[token];
    const int pos = atomicAdd(&cursor[a], 1);
    const int row = offsets[a] + pos;
    ridx[row] = token;
    srow = row;
  }
  __syncthreads();
  const int row = srow;
  const int j = threadIdx.x * 4;
  const float4 v = *reinterpret_cast<const float4*>(x + (size_t)token * DIM + j);
  ushort4 o;
  o.x = f2bf(v.x); o.y = f2bf(v.y); o.z = f2bf(v.z); o.w = f2bf(v.w);
  *reinterpret_cast<ushort4*>(Xb + (size_t)row * DIM + j) = o;
}

// ---------------- out pre-init: out = x + b2[e]*se  (split-K partial target) ----------
__global__ __launch_bounds__(256) void out_init_kernel(
    const float* __restrict__ x, const float* __restrict__ b2,
    const float* __restrict__ res_scale, const int* __restrict__ assign,
    float* __restrict__ out) {
  const int t = blockIdx.x;
  const int e = assign[t];
  const float se = res_scale[e];
  const int c = threadIdx.x * 4;
  const float4 xv = *reinterpret_cast<const float4*>(x + (size_t)t * DIM + c);
  const float4 bv = *reinterpret_cast<const float4*>(b2 + (size_t)e * DIM + c);
  float4 o;
  o.x = xv.x + bv.x * se; o.y = xv.y + bv.y * se;
  o.z = xv.z + bv.z * se; o.w = xv.w + bv.w * se;
  *reinterpret_cast<float4*>(out + (size_t)t * DIM + c) = o;
}

// ---------------- grouped GEMM1: H = Xb @ W1e^T + b1  (bf16 out, LDS-swizzled) ------
__global__ __launch_bounds__(256) void gemm1_kernel(
    const unsigned short* __restrict__ Xb, const unsigned short* __restrict__ W1b,
    const float* __restrict__ b1, const int* __restrict__ ctrl,
    unsigned short* __restrict__ Hb) {
  const int ti = blockIdx.y;
  if (ti >= ctrl[25]) return;
  const int e = ctrl[32 + ti];
  const int m_tile = ctrl[128 + ti];
  const int base = ctrl[16 + e];
  const int count = ctrl[16 + e + 1] - base;
  const int n0 = blockIdx.x * 128;
  constexpr int K = DIM;
  __shared__ unsigned short As[128 * 64];
  __shared__ unsigned short Bs[128 * 64];
  const int tid = threadIdx.x;
  const int wave = tid >> 6, lane = tid & 63;
  const int wr = wave >> 1, wc = wave & 1;
  f32x4 acc[4][4] = {};
  const unsigned short* Ag = Xb + (size_t)(base + m_tile * 128) * K;
  const unsigned short* Bg = W1b + ((size_t)e * FF + n0) * K;
  const int arow = lane >> 3;
  // pre-swizzled SOURCE column so linear global_load_lds yields st-swizzled LDS (T2 + rule#21)
  const int acolS = (((lane & 7) ^ arow) * 8);
  const int l7 = lane & 7;   // == row&7 for all fragment rows this lane reads
  const int jb = lane >> 4;
  for (int k0 = 0; k0 < K; k0 += 64) {
    __syncthreads();
#pragma unroll
    for (int it = 0; it < 4; ++it) {
      const int c = it * 4 + wave;          // wave-uniform chunk id
      const int r = c * 8 + arow;
      gload_lds16(Ag + (size_t)r * K + k0 + acolS, &As[c * 512]);
      gload_lds16(Bg + (size_t)r * K + k0 + acolS, &Bs[c * 512]);
    }
    __syncthreads();
#pragma unroll
    for (int kk = 0; kk < 64; kk += 32) {
      short8 a[4], b[4];
      const int j0 = (kk >> 3) + jb;
      const int js = (j0 ^ l7) << 3;        // swizzled 8-elem chunk offset
#pragma unroll
      for (int i = 0; i < 4; ++i)
        a[i] = *reinterpret_cast<const short8*>(
            &As[(wr * 64 + i * 16 + (lane & 15)) * 64 + js]);
#pragma unroll
      for (int j = 0; j < 4; ++j)
        b[j] = *reinterpret_cast<const short8*>(
            &Bs[(wc * 64 + j * 16 + (lane & 15)) * 64 + js]);
#pragma unroll
      for (int i = 0; i < 4; ++i)
#pragma unroll
        for (int j = 0; j < 4; ++j)
          acc[i][j] = __builtin_amdgcn_mfma_f32_16x16x32_bf16(a[i], b[j], acc[i][j], 0, 0, 0);
    }
  }
  const float* b1e = b1 + (size_t)e * FF;
  const int rbase = m_tile * 128 + wr * 64 + (lane >> 4) * 4;
  const int cbase = n0 + wc * 64 + (lane & 15);
#pragma unroll
  for (int i = 0; i < 4; ++i) {
#pragma unroll
    for (int j = 0; j < 4; ++j) {
      const int col = cbase + j * 16;
      const float bias = b1e[col];
#pragma unroll
      for (int r = 0; r < 4; ++r) {
        const int lr = rbase + i * 16 + r;
        if (lr < count)
          Hb[(size_t)(base + lr) * FF + col] = f2bf(acc[i][j][r] + bias);
      }
    }
  }
}

// ---------------- LayerNorm + exact GELU, in place on Hb ----------------
__global__ __launch_bounds__(256) void ln_gelu_kernel(
    unsigned short* __restrict__ Hb, const float* __restrict__ ln_g,
    const float* __restrict__ ln_b, const int* __restrict__ offsets) {
  const int row = blockIdx.x;
  int e = 0;
#pragma unroll
  for (int i = 1; i < NE; ++i) e += (row >= offsets[i]) ? 1 : 0;
  unsigned short* h = Hb + (size_t)row * FF;
  const int tid = threadIdx.x;
  const int lane = tid & 63, wave = tid >> 6;
  float v[8];
  float sum = 0.f, sq = 0.f;
  short8 raw = *reinterpret_cast<const short8*>(h + tid * 8);
#pragma unroll
  for (int i = 0; i < 8; ++i) {
    v[i] = bf2f((unsigned short)raw[i]);
    sum += v[i]; sq += v[i] * v[i];
  }
#pragma unroll
  for (int s = 32; s; s >>= 1) { sum += __shfl_xor(sum, s); sq += __shfl_xor(sq, s); }
  __shared__ float red[8];
  if (lane == 0) { red[wave] = sum; red[wave + 4] = sq; }
  __syncthreads();
  sum = red[0] + red[1] + red[2] + red[3];
  sq  = red[4] + red[5] + red[6] + red[7];
  const float mu = sum * (1.f / FF);
  const float var = sq * (1.f / FF) - mu * mu;
  const float rstd = rsqrtf(var + 1e-5f);
  const float* ge = ln_g + (size_t)e * FF + tid * 8;
  const float* be = ln_b + (size_t)e * FF + tid * 8;
  short8 outv;
#pragma unroll
  for (int i = 0; i < 8; ++i) {
    const float t = (v[i] - mu) * rstd * ge[i] + be[i];
    const float g = 0.5f * t * (1.f + erff(t * 0.70710678118f));
    outv[i] = (short)f2bf(g);
  }
  *reinterpret_cast<short8*>(h + tid * 8) = outv;
}

// ---------------- grouped GEMM2 (split-K=2): out += se * (Hb @ W2e^T) ----------------
__global__ __launch_bounds__(256) void gemm2_kernel(
    const unsigned short* __restrict__ Hb, const unsigned short* __restrict__ W2b,
    const int* __restrict__ ctrl, const int* __restrict__ ridx,
    const float* __restrict__ res_scale, float* __restrict__ out) {
  const int ti = blockIdx.y;
  if (ti >= ctrl[25]) return;
  const int e = ctrl[32 + ti];
  const int m_tile = ctrl[128 + ti];
  const int base = ctrl[16 + e];
  const int count = ctrl[16 + e + 1] - base;
  const int n0 = blockIdx.x * 128;
  constexpr int K = FF;
  const int kbeg = blockIdx.z * (K / 2);
  const int kend = kbeg + (K / 2);
  __shared__ unsigned short As[128 * 64];
  __shared__ unsigned short Bs[128 * 64];
  const int tid = threadIdx.x;
  const int wave = tid >> 6, lane = tid & 63;
  const int wr = wave >> 1, wc = wave & 1;
  f32x4 acc[4][4] = {};
  const unsigned short* Ag = Hb + (size_t)(base + m_tile * 128) * K;
  const unsigned short* Bg = W2b + ((size_t)e * DIM + n0) * K;
  const int arow = lane >> 3;
  const int acolS = (((lane & 7) ^ arow) * 8);
  const int l7 = lane & 7;
  const int jb = lane >> 4;
  for (int k0 = kbeg; k0 < kend; k0 += 64) {
    __syncthreads();
#pragma unroll
    for (int it = 0; it < 4; ++it) {
      const int c = it * 4 + wave;
      const int r = c * 8 + arow;
      gload_lds16(Ag + (size_t)r * K + k0 + acolS, &As[c * 512]);
      gload_lds16(Bg + (size_t)r * K + k0 + acolS, &Bs[c * 512]);
    }
    __syncthreads();
#pragma unroll
    for (int kk = 0; kk < 64; kk += 32) {
      short8 a[4], b[4];
      const int j0 = (kk >> 3) + jb;
      const int js = (j0 ^ l7) << 3;
#pragma unroll
      for (int i = 0; i < 4; ++i)
        a[i] = *reinterpret_cast<const short8*>(
            &As[(wr * 64 + i * 16 + (lane & 15)) * 64 + js]);
#pragma unroll
      for (int j = 0; j < 4; ++j)
        b[j] = *reinterpret_cast<const short8*>(
            &Bs[(wc * 64 + j * 16 + (lane & 15)) * 64 + js]);
#pragma unroll
      for (int i = 0; i < 4; ++i)
#pragma unroll
        for (int j = 0; j < 4; ++j)
          acc[i][j] = __builtin_amdgcn_mfma_f32_16x16x32_bf16(a[i], b[j], acc[i][j], 0, 0, 0);
    }
  }
  const float se = res_scale[e];
  const int rbase = m_tile * 128 + wr * 64 + (lane >> 4) * 4;
  const int cbase = n0 + wc * 64 + (lane & 15);
#pragma unroll
  for (int i = 0; i < 4; ++i) {
#pragma unroll
    for (int r = 0; r < 4; ++r) {
      const int lr = rbase + i * 16 + r;
      if (lr < count) {
        const int trow = ridx[base + lr];
        float* orow = out + (size_t)trow * DIM;
#pragma unroll
        for (int j = 0; j < 4; ++j)
          atomicAdd(&orow[cbase + j * 16], se * acc[i][j][r]);
      }
    }
  }
}

extern "C" void kernel_launch(void* const* d_in, const int* in_sizes, int n_in,
                              void* d_out, int out_size, void* d_ws, size_t ws_size,
                              hipStream_t stream) {
  const float* x         = (const float*)d_in[0];
  const float* Wg        = (const float*)d_in[1];
  const float* bg        = (const float*)d_in[2];
  const float* W1        = (const float*)d_in[3];
  const float* b1        = (const float*)d_in[4];
  const float* ln_g      = (const float*)d_in[5];
  const float* ln_b      = (const float*)d_in[6];
  const float* W2        = (const float*)d_in[7];
  const float* b2        = (const float*)d_in[8];
  const float* res_scale = (const float*)d_in[9];
  float* out = (float*)d_out;

  char* ws = (char*)d_ws;
  unsigned short* W1b = (unsigned short*)(ws);
  unsigned short* W2b = (unsigned short*)(ws + 33554432);
  unsigned short* Xb  = (unsigned short*)(ws + 67108864);
  unsigned short* Hb  = (unsigned short*)(ws + 83886080);
  int* assign  = (int*)(ws + 117964800);
  int* ridx    = (int*)(ws + 117997568);
  int* ctrl    = (int*)(ws + 118030336);

  hipMemsetAsync(ctrl, 0, 64, stream);  // counts + cursor
  convert_kernel<<<2048, 256, 0, stream>>>(W1, W1b, NE * FF * DIM);
  convert_kernel<<<2048, 256, 0, stream>>>(W2, W2b, NE * DIM * FF);
  gate_kernel<<<TOK / 4, 256, 0, stream>>>(x, Wg, bg, assign, ctrl);
  scan_kernel<<<1, 64, 0, stream>>>(ctrl);
  gather_kernel<<<TOK, 256, 0, stream>>>(x, assign, ctrl + 16, ctrl + 8, ridx, Xb);
  out_init_kernel<<<TOK, 256, 0, stream>>>(x, b2, res_scale, assign, out);
  gemm1_kernel<<<dim3(16, MAXTILES, 1), 256, 0, stream>>>(Xb, W1b, b1, ctrl, Hb);
  ln_gelu_kernel<<<TOK, 256, 0, stream>>>(Hb, ln_g, ln_b, ctrl + 16);
  gemm2_kernel<<<dim3(8, MAXTILES, 2), 256, 0, stream>>>(Hb, W2b, ctrl, ridx, res_scale, out);
}

// Round 3
// 473.404 us; speedup vs baseline: 1.1459x; 1.0622x over previous
//
#include <hip/hip_runtime.h>
#include <hip/hip_bf16.h>
#include <cstdint>
#include <cstddef>

#define TOK 8192
#define DIM 1024
#define FF  2048
#define NE  8
#define MAXTILES 72

typedef __attribute__((ext_vector_type(8))) short short8;
typedef __attribute__((ext_vector_type(4))) float f32x4;

__device__ inline void gload_lds16(const void* g, void* l) {
  __builtin_amdgcn_global_load_lds(
      (const __attribute__((address_space(1))) unsigned int*)g,
      (__attribute__((address_space(3))) unsigned int*)l, 16, 0, 0);
}

__device__ inline unsigned short f2bf(float f) {
  unsigned int u = __float_as_uint(f);
  u += 0x7fffu + ((u >> 16) & 1u);   // RNE
  return (unsigned short)(u >> 16);
}
__device__ inline float bf2f(unsigned short u) {
  return __uint_as_float(((unsigned int)u) << 16);
}

// ---------------- weight fp32 -> bf16 ----------------
__global__ __launch_bounds__(256) void convert_kernel(
    const float* __restrict__ src, unsigned short* __restrict__ dst, int n) {
  const int stride = gridDim.x * blockDim.x * 4;
  for (int i = (blockIdx.x * blockDim.x + threadIdx.x) * 4; i < n; i += stride) {
    const float4 v = *reinterpret_cast<const float4*>(src + i);
    ushort4 o;
    o.x = f2bf(v.x); o.y = f2bf(v.y); o.z = f2bf(v.z); o.w = f2bf(v.w);
    *reinterpret_cast<ushort4*>(dst + i) = o;
  }
}

// ---------------- gating: logits, top-2 (highest index wins), counts ----------------
__global__ __launch_bounds__(256) void gate_kernel(
    const float* __restrict__ x, const float* __restrict__ Wg,
    const float* __restrict__ bg, int* __restrict__ assign,
    int* __restrict__ counts) {
  const int token = blockIdx.x * 4 + (threadIdx.x >> 6);
  const int lane = threadIdx.x & 63;
  if (token >= TOK) return;
  const float* xr = x + (size_t)token * DIM;
  float acc[NE];
#pragma unroll
  for (int e = 0; e < NE; ++e) acc[e] = 0.f;
#pragma unroll
  for (int i0 = 0; i0 < DIM; i0 += 256) {
    const int i = i0 + lane * 4;
    const float4 xv = *reinterpret_cast<const float4*>(xr + i);
#pragma unroll
    for (int e = 0; e < NE; ++e) {
      const float4 wv = *reinterpret_cast<const float4*>(Wg + e * DIM + i);
      acc[e] += xv.x * wv.x + xv.y * wv.y + xv.z * wv.z + xv.w * wv.w;
    }
  }
#pragma unroll
  for (int e = 0; e < NE; ++e) {
    float v = acc[e];
#pragma unroll
    for (int s = 32; s; s >>= 1) v += __shfl_xor(v, s);
    acc[e] = v + bg[e];
  }
  if (lane == 0) {
    float v1 = -INFINITY, v2 = -INFINITY; int i1 = 0, i2 = 0;
#pragma unroll
    for (int e = 0; e < NE; ++e) {
      const float v = acc[e];
      if (v > v1)      { v2 = v1; i2 = i1; v1 = v; i1 = e; }
      else if (v > v2) { v2 = v; i2 = e; }
    }
    const int a = (i1 > i2) ? i1 : i2;   // max(top2 indices); softmax-sum weight == 1.0
    assign[token] = a;
    atomicAdd(&counts[a], 1);
  }
}

// ---------------- prefix scan + tile table ----------------
// ctrl: [0..7]=counts, [8..15]=cursor, [16..24]=offsets, [25]=ntiles,
//       [32..103]=tile_e, [128..199]=tile_m
__global__ void scan_kernel(int* __restrict__ ctrl) {
  if (threadIdx.x == 0 && blockIdx.x == 0) {
    int s = 0, nt = 0;
#pragma unroll
    for (int e = 0; e < NE; ++e) {
      ctrl[16 + e] = s;
      const int cnt = ctrl[e];
      for (int m = 0; m * 128 < cnt; ++m) {
        ctrl[32 + nt] = e;
        ctrl[128 + nt] = m;
        ++nt;
      }
      s += cnt;
    }
    ctrl[24] = s;
    ctrl[25] = nt;
  }
}

// ---------------- gather tokens into expert-contiguous bf16 rows ----------------
__global__ __launch_bounds__(256) void gather_kernel(
    const float* __restrict__ x, const int* __restrict__ assign,
    const int* __restrict__ offsets, int* __restrict__ cursor,
    int* __restrict__ ridx, unsigned short* __restrict__ Xb) {
  const int token = blockIdx.x;
  __shared__ int srow;
  if (threadIdx.x == 0) {
    const int a = assign[token];
    const int pos = atomicAdd(&cursor[a], 1);
    const int row = offsets[a] + pos;
    ridx[row] = token;
    srow = row;
  }
  __syncthreads();
  const int row = srow;
  const int j = threadIdx.x * 4;
  const float4 v = *reinterpret_cast<const float4*>(x + (size_t)token * DIM + j);
  ushort4 o;
  o.x = f2bf(v.x); o.y = f2bf(v.y); o.z = f2bf(v.z); o.w = f2bf(v.w);
  *reinterpret_cast<ushort4*>(Xb + (size_t)row * DIM + j) = o;
}

// ---------------- grouped GEMM1: H = Xb @ W1e^T + b1 (bf16 out) ----------------
// 128x128 tile, BK=64, double-buffered LDS, issue-early staging, 1 barrier/K-step.
__global__ __launch_bounds__(256) void gemm1_kernel(
    const unsigned short* __restrict__ Xb, const unsigned short* __restrict__ W1b,
    const float* __restrict__ b1, const int* __restrict__ ctrl,
    unsigned short* __restrict__ Hb) {
  // bijective XCD-chunk swizzle: grid = 16 * MAXTILES (divisible by 8)
  const int b = blockIdx.x;
  const int lid = (b & 7) * ((16 * MAXTILES) >> 3) + (b >> 3);
  const int nx = lid & 15;
  const int ti = lid >> 4;
  if (ti >= ctrl[25]) return;
  const int e = ctrl[32 + ti];
  const int m_tile = ctrl[128 + ti];
  const int base = ctrl[16 + e];
  const int count = ctrl[16 + e + 1] - base;
  const int n0 = nx * 128;
  constexpr int K = DIM;
  constexpr int NT = K / 64;
  __shared__ unsigned short As[2][128 * 64];
  __shared__ unsigned short Bs[2][128 * 64];
  const int tid = threadIdx.x;
  const int wave = tid >> 6, lane = tid & 63;
  const int wr = wave >> 1, wc = wave & 1;
  f32x4 acc[4][4] = {};
  const unsigned short* Ag = Xb + (size_t)(base + m_tile * 128) * K;
  const unsigned short* Bg = W1b + ((size_t)e * FF + n0) * K;
  const int arow = lane >> 3;
  const int acolS = (((lane & 7) ^ arow) * 8);   // pre-swizzled source col (T2 + rule#21)
  const int l7 = lane & 7;
  const int jb = lane >> 4;

#pragma unroll
  for (int it = 0; it < 4; ++it) {               // prologue stage -> buf0
    const int c = it * 4 + wave;
    const int r = c * 8 + arow;
    gload_lds16(Ag + (size_t)r * K + acolS, &As[0][c * 512]);
    gload_lds16(Bg + (size_t)r * K + acolS, &Bs[0][c * 512]);
  }
  __syncthreads();                               // drains vmcnt(0)

  int cur = 0;
  for (int t = 0; t + 1 < NT; ++t) {
    const int k1 = (t + 1) * 64;
#pragma unroll
    for (int it = 0; it < 4; ++it) {             // issue next tile EARLY
      const int c = it * 4 + wave;
      const int r = c * 8 + arow;
      gload_lds16(Ag + (size_t)r * K + k1 + acolS, &As[cur ^ 1][c * 512]);
      gload_lds16(Bg + (size_t)r * K + k1 + acolS, &Bs[cur ^ 1][c * 512]);
    }
#pragma unroll
    for (int kk = 0; kk < 64; kk += 32) {        // compute current tile
      short8 a[4], bb[4];
      const int js = (((kk >> 3) + jb) ^ l7) << 3;
#pragma unroll
      for (int i = 0; i < 4; ++i)
        a[i] = *reinterpret_cast<const short8*>(
            &As[cur][(wr * 64 + i * 16 + (lane & 15)) * 64 + js]);
#pragma unroll
      for (int j = 0; j < 4; ++j)
        bb[j] = *reinterpret_cast<const short8*>(
            &Bs[cur][(wc * 64 + j * 16 + (lane & 15)) * 64 + js]);
#pragma unroll
      for (int i = 0; i < 4; ++i)
#pragma unroll
        for (int j = 0; j < 4; ++j)
          acc[i][j] = __builtin_amdgcn_mfma_f32_16x16x32_bf16(a[i], bb[j], acc[i][j], 0, 0, 0);
    }
    __syncthreads();                             // next buf ready + current reads done
    cur ^= 1;
  }
#pragma unroll
  for (int kk = 0; kk < 64; kk += 32) {          // epilogue compute (last tile)
    short8 a[4], bb[4];
    const int js = (((kk >> 3) + jb) ^ l7) << 3;
#pragma unroll
    for (int i = 0; i < 4; ++i)
      a[i] = *reinterpret_cast<const short8*>(
          &As[cur][(wr * 64 + i * 16 + (lane & 15)) * 64 + js]);
#pragma unroll
    for (int j = 0; j < 4; ++j)
      bb[j] = *reinterpret_cast<const short8*>(
          &Bs[cur][(wc * 64 + j * 16 + (lane & 15)) * 64 + js]);
#pragma unroll
    for (int i = 0; i < 4; ++i)
#pragma unroll
      for (int j = 0; j < 4; ++j)
        acc[i][j] = __builtin_amdgcn_mfma_f32_16x16x32_bf16(a[i], bb[j], acc[i][j], 0, 0, 0);
  }

  const float* b1e = b1 + (size_t)e * FF;
  const int rbase = m_tile * 128 + wr * 64 + (lane >> 4) * 4;
  const int cbase = n0 + wc * 64 + (lane & 15);
#pragma unroll
  for (int i = 0; i < 4; ++i) {
#pragma unroll
    for (int j = 0; j < 4; ++j) {
      const int col = cbase + j * 16;
      const float bias = b1e[col];
#pragma unroll
      for (int r = 0; r < 4; ++r) {
        const int lr = rbase + i * 16 + r;
        if (lr < count)
          Hb[(size_t)(base + lr) * FF + col] = f2bf(acc[i][j][r] + bias);
      }
    }
  }
}

// ---------------- LayerNorm + exact GELU, in place on Hb ----------------
__global__ __launch_bounds__(256) void ln_gelu_kernel(
    unsigned short* __restrict__ Hb, const float* __restrict__ ln_g,
    const float* __restrict__ ln_b, const int* __restrict__ offsets) {
  const int row = blockIdx.x;
  int e = 0;
#pragma unroll
  for (int i = 1; i < NE; ++i) e += (row >= offsets[i]) ? 1 : 0;
  unsigned short* h = Hb + (size_t)row * FF;
  const int tid = threadIdx.x;
  const int lane = tid & 63, wave = tid >> 6;
  float v[8];
  float sum = 0.f, sq = 0.f;
  short8 raw = *reinterpret_cast<const short8*>(h + tid * 8);
#pragma unroll
  for (int i = 0; i < 8; ++i) {
    v[i] = bf2f((unsigned short)raw[i]);
    sum += v[i]; sq += v[i] * v[i];
  }
#pragma unroll
  for (int s = 32; s; s >>= 1) { sum += __shfl_xor(sum, s); sq += __shfl_xor(sq, s); }
  __shared__ float red[8];
  if (lane == 0) { red[wave] = sum; red[wave + 4] = sq; }
  __syncthreads();
  sum = red[0] + red[1] + red[2] + red[3];
  sq  = red[4] + red[5] + red[6] + red[7];
  const float mu = sum * (1.f / FF);
  const float var = sq * (1.f / FF) - mu * mu;
  const float rstd = rsqrtf(var + 1e-5f);
  const float* ge = ln_g + (size_t)e * FF + tid * 8;
  const float* be = ln_b + (size_t)e * FF + tid * 8;
  short8 outv;
#pragma unroll
  for (int i = 0; i < 8; ++i) {
    const float t = (v[i] - mu) * rstd * ge[i] + be[i];
    const float g = 0.5f * t * (1.f + erff(t * 0.70710678118f));
    outv[i] = (short)f2bf(g);
  }
  *reinterpret_cast<short8*>(h + tid * 8) = outv;
}

// ---------------- grouped GEMM2: out[t] = (Hb @ W2e^T + b2)*se + x[t] ----------------
__global__ __launch_bounds__(256) void gemm2_kernel(
    const unsigned short* __restrict__ Hb, const unsigned short* __restrict__ W2b,
    const float* __restrict__ b2, const float* __restrict__ res_scale,
    const int* __restrict__ ctrl, const int* __restrict__ ridx,
    const float* __restrict__ x, float* __restrict__ out) {
  const int b = blockIdx.x;
  const int lid = (b & 7) * ((8 * MAXTILES) >> 3) + (b >> 3);
  const int nx = lid & 7;
  const int ti = lid >> 3;
  if (ti >= ctrl[25]) return;
  const int e = ctrl[32 + ti];
  const int m_tile = ctrl[128 + ti];
  const int base = ctrl[16 + e];
  const int count = ctrl[16 + e + 1] - base;
  const int n0 = nx * 128;
  constexpr int K = FF;
  constexpr int NT = K / 64;
  __shared__ unsigned short As[2][128 * 64];
  __shared__ unsigned short Bs[2][128 * 64];
  const int tid = threadIdx.x;
  const int wave = tid >> 6, lane = tid & 63;
  const int wr = wave >> 1, wc = wave & 1;
  f32x4 acc[4][4] = {};
  const unsigned short* Ag = Hb + (size_t)(base + m_tile * 128) * K;
  const unsigned short* Bg = W2b + ((size_t)e * DIM + n0) * K;
  const int arow = lane >> 3;
  const int acolS = (((lane & 7) ^ arow) * 8);
  const int l7 = lane & 7;
  const int jb = lane >> 4;

#pragma unroll
  for (int it = 0; it < 4; ++it) {
    const int c = it * 4 + wave;
    const int r = c * 8 + arow;
    gload_lds16(Ag + (size_t)r * K + acolS, &As[0][c * 512]);
    gload_lds16(Bg + (size_t)r * K + acolS, &Bs[0][c * 512]);
  }
  __syncthreads();

  int cur = 0;
  for (int t = 0; t + 1 < NT; ++t) {
    const int k1 = (t + 1) * 64;
#pragma unroll
    for (int it = 0; it < 4; ++it) {
      const int c = it * 4 + wave;
      const int r = c * 8 + arow;
      gload_lds16(Ag + (size_t)r * K + k1 + acolS, &As[cur ^ 1][c * 512]);
      gload_lds16(Bg + (size_t)r * K + k1 + acolS, &Bs[cur ^ 1][c * 512]);
    }
#pragma unroll
    for (int kk = 0; kk < 64; kk += 32) {
      short8 a[4], bb[4];
      const int js = (((kk >> 3) + jb) ^ l7) << 3;
#pragma unroll
      for (int i = 0; i < 4; ++i)
        a[i] = *reinterpret_cast<const short8*>(
            &As[cur][(wr * 64 + i * 16 + (lane & 15)) * 64 + js]);
#pragma unroll
      for (int j = 0; j < 4; ++j)
        bb[j] = *reinterpret_cast<const short8*>(
            &Bs[cur][(wc * 64 + j * 16 + (lane & 15)) * 64 + js]);
#pragma unroll
      for (int i = 0; i < 4; ++i)
#pragma unroll
        for (int j = 0; j < 4; ++j)
          acc[i][j] = __builtin_amdgcn_mfma_f32_16x16x32_bf16(a[i], bb[j], acc[i][j], 0, 0, 0);
    }
    __syncthreads();
    cur ^= 1;
  }
#pragma unroll
  for (int kk = 0; kk < 64; kk += 32) {
    short8 a[4], bb[4];
    const int js = (((kk >> 3) + jb) ^ l7) << 3;
#pragma unroll
    for (int i = 0; i < 4; ++i)
      a[i] = *reinterpret_cast<const short8*>(
          &As[cur][(wr * 64 + i * 16 + (lane & 15)) * 64 + js]);
#pragma unroll
    for (int j = 0; j < 4; ++j)
      bb[j] = *reinterpret_cast<const short8*>(
          &Bs[cur][(wc * 64 + j * 16 + (lane & 15)) * 64 + js]);
#pragma unroll
    for (int i = 0; i < 4; ++i)
#pragma unroll
      for (int j = 0; j < 4; ++j)
        acc[i][j] = __builtin_amdgcn_mfma_f32_16x16x32_bf16(a[i], bb[j], acc[i][j], 0, 0, 0);
  }

  const float* b2e = b2 + (size_t)e * DIM;
  const float se = res_scale[e];
  const int rbase = m_tile * 128 + wr * 64 + (lane >> 4) * 4;
  const int cbase = n0 + wc * 64 + (lane & 15);
#pragma unroll
  for (int i = 0; i < 4; ++i) {
#pragma unroll
    for (int r = 0; r < 4; ++r) {
      const int lr = rbase + i * 16 + r;
      if (lr < count) {
        const int trow = ridx[base + lr];
        const float* xrow = x + (size_t)trow * DIM;
        float* orow = out + (size_t)trow * DIM;
#pragma unroll
        for (int j = 0; j < 4; ++j) {
          const int col = cbase + j * 16;
          orow[col] = (acc[i][j][r] + b2e[col]) * se + xrow[col];
        }
      }
    }
  }
}

extern "C" void kernel_launch(void* const* d_in, const int* in_sizes, int n_in,
                              void* d_out, int out_size, void* d_ws, size_t ws_size,
                              hipStream_t stream) {
  const float* x         = (const float*)d_in[0];
  const float* Wg        = (const float*)d_in[1];
  const float* bg        = (const float*)d_in[2];
  const float* W1        = (const float*)d_in[3];
  const float* b1        = (const float*)d_in[4];
  const float* ln_g      = (const float*)d_in[5];
  const float* ln_b      = (const float*)d_in[6];
  const float* W2        = (const float*)d_in[7];
  const float* b2        = (const float*)d_in[8];
  const float* res_scale = (const float*)d_in[9];
  float* out = (float*)d_out;

  char* ws = (char*)d_ws;
  unsigned short* W1b = (unsigned short*)(ws);
  unsigned short* W2b = (unsigned short*)(ws + 33554432);
  unsigned short* Xb  = (unsigned short*)(ws + 67108864);
  unsigned short* Hb  = (unsigned short*)(ws + 83886080);
  int* assign  = (int*)(ws + 117964800);
  int* ridx    = (int*)(ws + 117997568);
  int* ctrl    = (int*)(ws + 118030336);

  hipMemsetAsync(ctrl, 0, 64, stream);  // counts + cursor
  convert_kernel<<<2048, 256, 0, stream>>>(W1, W1b, NE * FF * DIM);
  convert_kernel<<<2048, 256, 0, stream>>>(W2, W2b, NE * DIM * FF);
  gate_kernel<<<TOK / 4, 256, 0, stream>>>(x, Wg, bg, assign, ctrl);
  scan_kernel<<<1, 64, 0, stream>>>(ctrl);
  gather_kernel<<<TOK, 256, 0, stream>>>(x, assign, ctrl + 16, ctrl + 8, ridx, Xb);
  gemm1_kernel<<<16 * MAXTILES, 256, 0, stream>>>(Xb, W1b, b1, ctrl, Hb);
  ln_gelu_kernel<<<TOK, 256, 0, stream>>>(Hb, ln_g, ln_b, ctrl + 16);
  gemm2_kernel<<<8 * MAXTILES, 256, 0, stream>>>(Hb, W2b, b2, res_scale, ctrl, ridx, x, out);
}

// Round 4
// 293.015 us; speedup vs baseline: 1.8514x; 1.6156x over previous
//
#include <hip/hip_runtime.h>
#include <hip/hip_bf16.h>
#include <cstdint>
#include <cstddef>

#define TOK 8192
#define DIM 1024
#define FF  2048
#define NE  8
#define MAXTILES 72
#define NBLK 32            // count_rank blocks (256 tokens each)

typedef __attribute__((ext_vector_type(8))) short short8;
typedef __attribute__((ext_vector_type(4))) float f32x4;

__device__ inline void gload_lds16(const void* g, void* l) {
  __builtin_amdgcn_global_load_lds(
      (const __attribute__((address_space(1))) unsigned int*)g,
      (__attribute__((address_space(3))) unsigned int*)l, 16, 0, 0);
}

__device__ inline unsigned short f2bf(float f) {
  unsigned int u = __float_as_uint(f);
  u += 0x7fffu + ((u >> 16) & 1u);   // RNE
  return (unsigned short)(u >> 16);
}
__device__ inline float bf2f(unsigned short u) {
  return __uint_as_float(((unsigned int)u) << 16);
}

// ---------------- weight fp32 -> bf16 ----------------
__global__ __launch_bounds__(256) void convert_kernel(
    const float* __restrict__ src, unsigned short* __restrict__ dst, int n) {
  const int stride = gridDim.x * blockDim.x * 4;
  for (int i = (blockIdx.x * blockDim.x + threadIdx.x) * 4; i < n; i += stride) {
    const float4 v = *reinterpret_cast<const float4*>(src + i);
    ushort4 o;
    o.x = f2bf(v.x); o.y = f2bf(v.y); o.z = f2bf(v.z); o.w = f2bf(v.w);
    *reinterpret_cast<ushort4*>(dst + i) = o;
  }
}

// ---------------- gating: logits, top-2 (highest index wins) -- no atomics ----------
__global__ __launch_bounds__(256) void gate_kernel(
    const float* __restrict__ x, const float* __restrict__ Wg,
    const float* __restrict__ bg, int* __restrict__ assign) {
  const int token = blockIdx.x * 4 + (threadIdx.x >> 6);
  const int lane = threadIdx.x & 63;
  if (token >= TOK) return;
  const float* xr = x + (size_t)token * DIM;
  float acc[NE];
#pragma unroll
  for (int e = 0; e < NE; ++e) acc[e] = 0.f;
#pragma unroll
  for (int i0 = 0; i0 < DIM; i0 += 256) {
    const int i = i0 + lane * 4;
    const float4 xv = *reinterpret_cast<const float4*>(xr + i);
#pragma unroll
    for (int e = 0; e < NE; ++e) {
      const float4 wv = *reinterpret_cast<const float4*>(Wg + e * DIM + i);
      acc[e] += xv.x * wv.x + xv.y * wv.y + xv.z * wv.z + xv.w * wv.w;
    }
  }
#pragma unroll
  for (int e = 0; e < NE; ++e) {
    float v = acc[e];
#pragma unroll
    for (int s = 32; s; s >>= 1) v += __shfl_xor(v, s);
    acc[e] = v + bg[e];
  }
  if (lane == 0) {
    float v1 = -INFINITY, v2 = -INFINITY; int i1 = 0, i2 = 0;
#pragma unroll
    for (int e = 0; e < NE; ++e) {
      const float v = acc[e];
      if (v > v1)      { v2 = v1; i2 = i1; v1 = v; i1 = e; }
      else if (v > v2) { v2 = v; i2 = e; }
    }
    assign[token] = (i1 > i2) ? i1 : i2;  // max(top2 indices); softmax-sum weight == 1.0
  }
}

// ---------------- ballot-based per-block counts + in-block ranks (no atomics) -------
__global__ __launch_bounds__(256) void count_rank_kernel(
    const int* __restrict__ assign, int* __restrict__ rank,
    int* __restrict__ blkcnt) {
  const int blk = blockIdx.x;
  const int tid = threadIdx.x;
  const int t = blk * 256 + tid;
  const int lane = tid & 63, wave = tid >> 6;
  const int a = assign[t];
  __shared__ int wcnt[4][NE];
  int myrank = 0;
#pragma unroll
  for (int e = 0; e < NE; ++e) {
    const unsigned long long m = __ballot(a == e);
    if (a == e) myrank = __popcll(m & ((1ull << lane) - 1ull));
    if (lane == 0) wcnt[wave][e] = __popcll(m);
  }
  __syncthreads();
  int pre = 0;
  for (int w = 0; w < wave; ++w) pre += wcnt[w][a];
  rank[t] = pre + myrank;
  if (tid < NE)
    blkcnt[blk * NE + tid] = wcnt[0][tid] + wcnt[1][tid] + wcnt[2][tid] + wcnt[3][tid];
}

// ---------------- scan: block offsets, expert offsets, tile table ----------------
// ctrl: [16..24]=offsets, [25]=ntiles, [32..103]=tile_e, [128..199]=tile_m
__global__ void scan2_kernel(int* __restrict__ ctrl, const int* __restrict__ blkcnt,
                             int* __restrict__ blkoff) {
  const int tid = threadIdx.x;
  __shared__ int ecnt[NE];
  if (tid < NE) {
    int run = 0;
    for (int b = 0; b < NBLK; ++b) {
      blkoff[b * NE + tid] = run;
      run += blkcnt[b * NE + tid];
    }
    ecnt[tid] = run;
  }
  __syncthreads();
  if (tid == 0) {
    int s = 0, nt = 0;
#pragma unroll
    for (int e = 0; e < NE; ++e) {
      ctrl[16 + e] = s;
      const int cnt = ecnt[e];
      for (int m = 0; m * 128 < cnt; ++m) {
        ctrl[32 + nt] = e;
        ctrl[128 + nt] = m;
        ++nt;
      }
      s += cnt;
    }
    ctrl[24] = s;
    ctrl[25] = nt;
  }
  __syncthreads();
  if (tid < NE) {
    const int off = ctrl[16 + tid];
    for (int b = 0; b < NBLK; ++b) blkoff[b * NE + tid] += off;
  }
}

// ---------------- gather tokens into expert-contiguous bf16 rows (no atomics) -------
__global__ __launch_bounds__(256) void gather_kernel(
    const float* __restrict__ x, const int* __restrict__ assign,
    const int* __restrict__ rank, const int* __restrict__ blkoff,
    int* __restrict__ ridx, unsigned short* __restrict__ Xb) {
  const int token = blockIdx.x;
  const int a = assign[token];
  const int row = blkoff[(token >> 8) * NE + a] + rank[token];
  if (threadIdx.x == 0) ridx[row] = token;
  const int j = threadIdx.x * 4;
  const float4 v = *reinterpret_cast<const float4*>(x + (size_t)token * DIM + j);
  ushort4 o;
  o.x = f2bf(v.x); o.y = f2bf(v.y); o.z = f2bf(v.z); o.w = f2bf(v.w);
  *reinterpret_cast<ushort4*>(Xb + (size_t)row * DIM + j) = o;
}

// ---------------- grouped GEMM1: H = Xb @ W1e^T + b1 (bf16 out) ----------------
// 128x128 tile, BK=64, double-buffered LDS, issue-early staging, 1 barrier/K-step.
__global__ __launch_bounds__(256) void gemm1_kernel(
    const unsigned short* __restrict__ Xb, const unsigned short* __restrict__ W1b,
    const float* __restrict__ b1, const int* __restrict__ ctrl,
    unsigned short* __restrict__ Hb) {
  const int b = blockIdx.x;
  const int lid = (b & 7) * ((16 * MAXTILES) >> 3) + (b >> 3);
  const int nx = lid & 15;
  const int ti = lid >> 4;
  if (ti >= ctrl[25]) return;
  const int e = ctrl[32 + ti];
  const int m_tile = ctrl[128 + ti];
  const int base = ctrl[16 + e];
  const int count = ctrl[16 + e + 1] - base;
  const int n0 = nx * 128;
  constexpr int K = DIM;
  constexpr int NT = K / 64;
  __shared__ unsigned short As[2][128 * 64];
  __shared__ unsigned short Bs[2][128 * 64];
  const int tid = threadIdx.x;
  const int wave = tid >> 6, lane = tid & 63;
  const int wr = wave >> 1, wc = wave & 1;
  f32x4 acc[4][4] = {};
  const unsigned short* Ag = Xb + (size_t)(base + m_tile * 128) * K;
  const unsigned short* Bg = W1b + ((size_t)e * FF + n0) * K;
  const int arow = lane >> 3;
  const int acolS = (((lane & 7) ^ arow) * 8);   // pre-swizzled source col (T2 + rule#21)
  const int l7 = lane & 7;
  const int jb = lane >> 4;

#pragma unroll
  for (int it = 0; it < 4; ++it) {               // prologue stage -> buf0
    const int c = it * 4 + wave;
    const int r = c * 8 + arow;
    gload_lds16(Ag + (size_t)r * K + acolS, &As[0][c * 512]);
    gload_lds16(Bg + (size_t)r * K + acolS, &Bs[0][c * 512]);
  }
  __syncthreads();

  int cur = 0;
  for (int t = 0; t + 1 < NT; ++t) {
    const int k1 = (t + 1) * 64;
#pragma unroll
    for (int it = 0; it < 4; ++it) {             // issue next tile EARLY
      const int c = it * 4 + wave;
      const int r = c * 8 + arow;
      gload_lds16(Ag + (size_t)r * K + k1 + acolS, &As[cur ^ 1][c * 512]);
      gload_lds16(Bg + (size_t)r * K + k1 + acolS, &Bs[cur ^ 1][c * 512]);
    }
#pragma unroll
    for (int kk = 0; kk < 64; kk += 32) {        // compute current tile
      short8 a[4], bb[4];
      const int js = (((kk >> 3) + jb) ^ l7) << 3;
#pragma unroll
      for (int i = 0; i < 4; ++i)
        a[i] = *reinterpret_cast<const short8*>(
            &As[cur][(wr * 64 + i * 16 + (lane & 15)) * 64 + js]);
#pragma unroll
      for (int j = 0; j < 4; ++j)
        bb[j] = *reinterpret_cast<const short8*>(
            &Bs[cur][(wc * 64 + j * 16 + (lane & 15)) * 64 + js]);
#pragma unroll
      for (int i = 0; i < 4; ++i)
#pragma unroll
        for (int j = 0; j < 4; ++j)
          acc[i][j] = __builtin_amdgcn_mfma_f32_16x16x32_bf16(a[i], bb[j], acc[i][j], 0, 0, 0);
    }
    __syncthreads();
    cur ^= 1;
  }
#pragma unroll
  for (int kk = 0; kk < 64; kk += 32) {          // epilogue compute (last tile)
    short8 a[4], bb[4];
    const int js = (((kk >> 3) + jb) ^ l7) << 3;
#pragma unroll
    for (int i = 0; i < 4; ++i)
      a[i] = *reinterpret_cast<const short8*>(
          &As[cur][(wr * 64 + i * 16 + (lane & 15)) * 64 + js]);
#pragma unroll
    for (int j = 0; j < 4; ++j)
      bb[j] = *reinterpret_cast<const short8*>(
          &Bs[cur][(wc * 64 + j * 16 + (lane & 15)) * 64 + js]);
#pragma unroll
    for (int i = 0; i < 4; ++i)
#pragma unroll
      for (int j = 0; j < 4; ++j)
        acc[i][j] = __builtin_amdgcn_mfma_f32_16x16x32_bf16(a[i], bb[j], acc[i][j], 0, 0, 0);
  }

  const float* b1e = b1 + (size_t)e * FF;
  const int rbase = m_tile * 128 + wr * 64 + (lane >> 4) * 4;
  const int cbase = n0 + wc * 64 + (lane & 15);
#pragma unroll
  for (int i = 0; i < 4; ++i) {
#pragma unroll
    for (int j = 0; j < 4; ++j) {
      const int col = cbase + j * 16;
      const float bias = b1e[col];
#pragma unroll
      for (int r = 0; r < 4; ++r) {
        const int lr = rbase + i * 16 + r;
        if (lr < count)
          Hb[(size_t)(base + lr) * FF + col] = f2bf(acc[i][j][r] + bias);
      }
    }
  }
}

// ---------------- LayerNorm + exact GELU, in place on Hb ----------------
__global__ __launch_bounds__(256) void ln_gelu_kernel(
    unsigned short* __restrict__ Hb, const float* __restrict__ ln_g,
    const float* __restrict__ ln_b, const int* __restrict__ offsets) {
  const int row = blockIdx.x;
  int e = 0;
#pragma unroll
  for (int i = 1; i < NE; ++i) e += (row >= offsets[i]) ? 1 : 0;
  unsigned short* h = Hb + (size_t)row * FF;
  const int tid = threadIdx.x;
  const int lane = tid & 63, wave = tid >> 6;
  float v[8];
  float sum = 0.f, sq = 0.f;
  short8 raw = *reinterpret_cast<const short8*>(h + tid * 8);
#pragma unroll
  for (int i = 0; i < 8; ++i) {
    v[i] = bf2f((unsigned short)raw[i]);
    sum += v[i]; sq += v[i] * v[i];
  }
#pragma unroll
  for (int s = 32; s; s >>= 1) { sum += __shfl_xor(sum, s); sq += __shfl_xor(sq, s); }
  __shared__ float red[8];
  if (lane == 0) { red[wave] = sum; red[wave + 4] = sq; }
  __syncthreads();
  sum = red[0] + red[1] + red[2] + red[3];
  sq  = red[4] + red[5] + red[6] + red[7];
  const float mu = sum * (1.f / FF);
  const float var = sq * (1.f / FF) - mu * mu;
  const float rstd = rsqrtf(var + 1e-5f);
  const float* ge = ln_g + (size_t)e * FF + tid * 8;
  const float* be = ln_b + (size_t)e * FF + tid * 8;
  short8 outv;
#pragma unroll
  for (int i = 0; i < 8; ++i) {
    const float t = (v[i] - mu) * rstd * ge[i] + be[i];
    const float g = 0.5f * t * (1.f + erff(t * 0.70710678118f));
    outv[i] = (short)f2bf(g);
  }
  *reinterpret_cast<short8*>(h + tid * 8) = outv;
}

// ---------------- grouped GEMM2: out[t] = (Hb @ W2e^T + b2)*se + x[t] ----------------
__global__ __launch_bounds__(256) void gemm2_kernel(
    const unsigned short* __restrict__ Hb, const unsigned short* __restrict__ W2b,
    const float* __restrict__ b2, const float* __restrict__ res_scale,
    const int* __restrict__ ctrl, const int* __restrict__ ridx,
    const float* __restrict__ x, float* __restrict__ out) {
  const int b = blockIdx.x;
  const int lid = (b & 7) * ((8 * MAXTILES) >> 3) + (b >> 3);
  const int nx = lid & 7;
  const int ti = lid >> 3;
  if (ti >= ctrl[25]) return;
  const int e = ctrl[32 + ti];
  const int m_tile = ctrl[128 + ti];
  const int base = ctrl[16 + e];
  const int count = ctrl[16 + e + 1] - base;
  const int n0 = nx * 128;
  constexpr int K = FF;
  constexpr int NT = K / 64;
  __shared__ unsigned short As[2][128 * 64];
  __shared__ unsigned short Bs[2][128 * 64];
  const int tid = threadIdx.x;
  const int wave = tid >> 6, lane = tid & 63;
  const int wr = wave >> 1, wc = wave & 1;
  f32x4 acc[4][4] = {};
  const unsigned short* Ag = Hb + (size_t)(base + m_tile * 128) * K;
  const unsigned short* Bg = W2b + ((size_t)e * DIM + n0) * K;
  const int arow = lane >> 3;
  const int acolS = (((lane & 7) ^ arow) * 8);
  const int l7 = lane & 7;
  const int jb = lane >> 4;

#pragma unroll
  for (int it = 0; it < 4; ++it) {
    const int c = it * 4 + wave;
    const int r = c * 8 + arow;
    gload_lds16(Ag + (size_t)r * K + acolS, &As[0][c * 512]);
    gload_lds16(Bg + (size_t)r * K + acolS, &Bs[0][c * 512]);
  }
  __syncthreads();

  int cur = 0;
  for (int t = 0; t + 1 < NT; ++t) {
    const int k1 = (t + 1) * 64;
#pragma unroll
    for (int it = 0; it < 4; ++it) {
      const int c = it * 4 + wave;
      const int r = c * 8 + arow;
      gload_lds16(Ag + (size_t)r * K + k1 + acolS, &As[cur ^ 1][c * 512]);
      gload_lds16(Bg + (size_t)r * K + k1 + acolS, &Bs[cur ^ 1][c * 512]);
    }
#pragma unroll
    for (int kk = 0; kk < 64; kk += 32) {
      short8 a[4], bb[4];
      const int js = (((kk >> 3) + jb) ^ l7) << 3;
#pragma unroll
      for (int i = 0; i < 4; ++i)
        a[i] = *reinterpret_cast<const short8*>(
            &As[cur][(wr * 64 + i * 16 + (lane & 15)) * 64 + js]);
#pragma unroll
      for (int j = 0; j < 4; ++j)
        bb[j] = *reinterpret_cast<const short8*>(
            &Bs[cur][(wc * 64 + j * 16 + (lane & 15)) * 64 + js]);
#pragma unroll
      for (int i = 0; i < 4; ++i)
#pragma unroll
        for (int j = 0; j < 4; ++j)
          acc[i][j] = __builtin_amdgcn_mfma_f32_16x16x32_bf16(a[i], bb[j], acc[i][j], 0, 0, 0);
    }
    __syncthreads();
    cur ^= 1;
  }
#pragma unroll
  for (int kk = 0; kk < 64; kk += 32) {
    short8 a[4], bb[4];
    const int js = (((kk >> 3) + jb) ^ l7) << 3;
#pragma unroll
    for (int i = 0; i < 4; ++i)
      a[i] = *reinterpret_cast<const short8*>(
          &As[cur][(wr * 64 + i * 16 + (lane & 15)) * 64 + js]);
#pragma unroll
    for (int j = 0; j < 4; ++j)
      bb[j] = *reinterpret_cast<const short8*>(
          &Bs[cur][(wc * 64 + j * 16 + (lane & 15)) * 64 + js]);
#pragma unroll
    for (int i = 0; i < 4; ++i)
#pragma unroll
      for (int j = 0; j < 4; ++j)
        acc[i][j] = __builtin_amdgcn_mfma_f32_16x16x32_bf16(a[i], bb[j], acc[i][j], 0, 0, 0);
  }

  const float* b2e = b2 + (size_t)e * DIM;
  const float se = res_scale[e];
  const int rbase = m_tile * 128 + wr * 64 + (lane >> 4) * 4;
  const int cbase = n0 + wc * 64 + (lane & 15);
#pragma unroll
  for (int i = 0; i < 4; ++i) {
#pragma unroll
    for (int r = 0; r < 4; ++r) {
      const int lr = rbase + i * 16 + r;
      if (lr < count) {
        const int trow = ridx[base + lr];
        const float* xrow = x + (size_t)trow * DIM;
        float* orow = out + (size_t)trow * DIM;
#pragma unroll
        for (int j = 0; j < 4; ++j) {
          const int col = cbase + j * 16;
          orow[col] = (acc[i][j][r] + b2e[col]) * se + xrow[col];
        }
      }
    }
  }
}

extern "C" void kernel_launch(void* const* d_in, const int* in_sizes, int n_in,
                              void* d_out, int out_size, void* d_ws, size_t ws_size,
                              hipStream_t stream) {
  const float* x         = (const float*)d_in[0];
  const float* Wg        = (const float*)d_in[1];
  const float* bg        = (const float*)d_in[2];
  const float* W1        = (const float*)d_in[3];
  const float* b1        = (const float*)d_in[4];
  const float* ln_g      = (const float*)d_in[5];
  const float* ln_b      = (const float*)d_in[6];
  const float* W2        = (const float*)d_in[7];
  const float* b2        = (const float*)d_in[8];
  const float* res_scale = (const float*)d_in[9];
  float* out = (float*)d_out;

  char* ws = (char*)d_ws;
  unsigned short* W1b = (unsigned short*)(ws);
  unsigned short* W2b = (unsigned short*)(ws + 33554432);
  unsigned short* Xb  = (unsigned short*)(ws + 67108864);
  unsigned short* Hb  = (unsigned short*)(ws + 83886080);
  int* assign  = (int*)(ws + 117964800);
  int* ridx    = (int*)(ws + 117997568);
  int* ctrl    = (int*)(ws + 118030336);
  int* rank    = (int*)(ws + 118034432);
  int* blkcnt  = (int*)(ws + 118067200);
  int* blkoff  = (int*)(ws + 118068224);

  gate_kernel<<<TOK / 4, 256, 0, stream>>>(x, Wg, bg, assign);
  convert_kernel<<<2048, 256, 0, stream>>>(W1, W1b, NE * FF * DIM);
  convert_kernel<<<2048, 256, 0, stream>>>(W2, W2b, NE * DIM * FF);
  count_rank_kernel<<<NBLK, 256, 0, stream>>>(assign, rank, blkcnt);
  scan2_kernel<<<1, 64, 0, stream>>>(ctrl, blkcnt, blkoff);
  gather_kernel<<<TOK, 256, 0, stream>>>(x, assign, rank, blkoff, ridx, Xb);
  gemm1_kernel<<<16 * MAXTILES, 256, 0, stream>>>(Xb, W1b, b1, ctrl, Hb);
  ln_gelu_kernel<<<TOK, 256, 0, stream>>>(Hb, ln_g, ln_b, ctrl + 16);
  gemm2_kernel<<<8 * MAXTILES, 256, 0, stream>>>(Hb, W2b, b2, res_scale, ctrl, ridx, x, out);
}

// Round 5
// 287.608 us; speedup vs baseline: 1.8862x; 1.0188x over previous
//
#include <hip/hip_runtime.h>
#include <hip/hip_bf16.h>
#include <cstdint>
#include <cstddef>

#define TOK 8192
#define DIM 1024
#define FF  2048
#define NE  8
#define MAXTILES 72
#define NBLK 32            // count_rank blocks (256 tokens each)

typedef __attribute__((ext_vector_type(8))) short short8;
typedef __attribute__((ext_vector_type(4))) float f32x4;

__device__ inline void gload_lds16(const void* g, void* l) {
  __builtin_amdgcn_global_load_lds(
      (const __attribute__((address_space(1))) unsigned int*)g,
      (__attribute__((address_space(3))) unsigned int*)l, 16, 0, 0);
}

__device__ inline unsigned short f2bf(float f) {
  unsigned int u = __float_as_uint(f);
  u += 0x7fffu + ((u >> 16) & 1u);   // RNE
  return (unsigned short)(u >> 16);
}
__device__ inline float bf2f(unsigned short u) {
  return __uint_as_float(((unsigned int)u) << 16);
}

// ---------------- weight fp32 -> bf16 ----------------
__global__ __launch_bounds__(256) void convert_kernel(
    const float* __restrict__ src, unsigned short* __restrict__ dst, int n) {
  const int stride = gridDim.x * blockDim.x * 4;
  for (int i = (blockIdx.x * blockDim.x + threadIdx.x) * 4; i < n; i += stride) {
    const float4 v = *reinterpret_cast<const float4*>(src + i);
    ushort4 o;
    o.x = f2bf(v.x); o.y = f2bf(v.y); o.z = f2bf(v.z); o.w = f2bf(v.w);
    *reinterpret_cast<ushort4*>(dst + i) = o;
  }
}

// ---------------- gating: logits, top-2 (highest index wins) -- no atomics ----------
__global__ __launch_bounds__(256) void gate_kernel(
    const float* __restrict__ x, const float* __restrict__ Wg,
    const float* __restrict__ bg, int* __restrict__ assign) {
  const int token = blockIdx.x * 4 + (threadIdx.x >> 6);
  const int lane = threadIdx.x & 63;
  if (token >= TOK) return;
  const float* xr = x + (size_t)token * DIM;
  float acc[NE];
#pragma unroll
  for (int e = 0; e < NE; ++e) acc[e] = 0.f;
#pragma unroll
  for (int i0 = 0; i0 < DIM; i0 += 256) {
    const int i = i0 + lane * 4;
    const float4 xv = *reinterpret_cast<const float4*>(xr + i);
#pragma unroll
    for (int e = 0; e < NE; ++e) {
      const float4 wv = *reinterpret_cast<const float4*>(Wg + e * DIM + i);
      acc[e] += xv.x * wv.x + xv.y * wv.y + xv.z * wv.z + xv.w * wv.w;
    }
  }
#pragma unroll
  for (int e = 0; e < NE; ++e) {
    float v = acc[e];
#pragma unroll
    for (int s = 32; s; s >>= 1) v += __shfl_xor(v, s);
    acc[e] = v + bg[e];
  }
  if (lane == 0) {
    float v1 = -INFINITY, v2 = -INFINITY; int i1 = 0, i2 = 0;
#pragma unroll
    for (int e = 0; e < NE; ++e) {
      const float v = acc[e];
      if (v > v1)      { v2 = v1; i2 = i1; v1 = v; i1 = e; }
      else if (v > v2) { v2 = v; i2 = e; }
    }
    assign[token] = (i1 > i2) ? i1 : i2;  // max(top2 indices); softmax-sum weight == 1.0
  }
}

// ---------------- ballot-based per-block counts + in-block ranks (no atomics) -------
__global__ __launch_bounds__(256) void count_rank_kernel(
    const int* __restrict__ assign, int* __restrict__ rank,
    int* __restrict__ blkcnt) {
  const int blk = blockIdx.x;
  const int tid = threadIdx.x;
  const int t = blk * 256 + tid;
  const int lane = tid & 63, wave = tid >> 6;
  const int a = assign[t];
  __shared__ int wcnt[4][NE];
  int myrank = 0;
#pragma unroll
  for (int e = 0; e < NE; ++e) {
    const unsigned long long m = __ballot(a == e);
    if (a == e) myrank = __popcll(m & ((1ull << lane) - 1ull));
    if (lane == 0) wcnt[wave][e] = __popcll(m);
  }
  __syncthreads();
  int pre = 0;
  for (int w = 0; w < wave; ++w) pre += wcnt[w][a];
  rank[t] = pre + myrank;
  if (tid < NE)
    blkcnt[blk * NE + tid] = wcnt[0][tid] + wcnt[1][tid] + wcnt[2][tid] + wcnt[3][tid];
}

// ---------------- scan: block offsets, expert offsets, tile table ----------------
// ctrl: [16..24]=offsets, [25]=ntiles, [32..103]=tile_e, [128..199]=tile_m
__global__ void scan2_kernel(int* __restrict__ ctrl, const int* __restrict__ blkcnt,
                             int* __restrict__ blkoff) {
  const int tid = threadIdx.x;
  __shared__ int ecnt[NE];
  if (tid < NE) {
    int run = 0;
    for (int b = 0; b < NBLK; ++b) {
      blkoff[b * NE + tid] = run;
      run += blkcnt[b * NE + tid];
    }
    ecnt[tid] = run;
  }
  __syncthreads();
  if (tid == 0) {
    int s = 0, nt = 0;
#pragma unroll
    for (int e = 0; e < NE; ++e) {
      ctrl[16 + e] = s;
      const int cnt = ecnt[e];
      for (int m = 0; m * 128 < cnt; ++m) {
        ctrl[32 + nt] = e;
        ctrl[128 + nt] = m;
        ++nt;
      }
      s += cnt;
    }
    ctrl[24] = s;
    ctrl[25] = nt;
  }
  __syncthreads();
  if (tid < NE) {
    const int off = ctrl[16 + tid];
    for (int b = 0; b < NBLK; ++b) blkoff[b * NE + tid] += off;
  }
}

// ---------------- gather tokens into expert-contiguous bf16 rows (no atomics) -------
__global__ __launch_bounds__(256) void gather_kernel(
    const float* __restrict__ x, const int* __restrict__ assign,
    const int* __restrict__ rank, const int* __restrict__ blkoff,
    int* __restrict__ ridx, unsigned short* __restrict__ Xb) {
  const int token = blockIdx.x;
  const int a = assign[token];
  const int row = blkoff[(token >> 8) * NE + a] + rank[token];
  if (threadIdx.x == 0) ridx[row] = token;
  const int j = threadIdx.x * 4;
  const float4 v = *reinterpret_cast<const float4*>(x + (size_t)token * DIM + j);
  ushort4 o;
  o.x = f2bf(v.x); o.y = f2bf(v.y); o.z = f2bf(v.z); o.w = f2bf(v.w);
  *reinterpret_cast<ushort4*>(Xb + (size_t)row * DIM + j) = o;
}

// ---------------- grouped GEMM1: H = Xb @ W1e^T + b1 (bf16 out) ----------------
// 128x128 tile, BK=64, dbuf, counted vmcnt(8) + raw s_barrier (loads fly across barrier)
__global__ __launch_bounds__(256) void gemm1_kernel(
    const unsigned short* __restrict__ Xb, const unsigned short* __restrict__ W1b,
    const float* __restrict__ b1, const int* __restrict__ ctrl,
    unsigned short* __restrict__ Hb) {
  const int b = blockIdx.x;
  const int lid = (b & 7) * ((16 * MAXTILES) >> 3) + (b >> 3);
  const int nx = lid & 15;
  const int ti = lid >> 4;
  if (ti >= ctrl[25]) return;
  const int e = ctrl[32 + ti];
  const int m_tile = ctrl[128 + ti];
  const int base = ctrl[16 + e];
  const int count = ctrl[16 + e + 1] - base;
  const int n0 = nx * 128;
  constexpr int K = DIM;
  constexpr int NT = K / 64;
  __shared__ unsigned short As[2][128 * 64];
  __shared__ unsigned short Bs[2][128 * 64];
  const int tid = threadIdx.x;
  const int wave = tid >> 6, lane = tid & 63;
  const int wr = wave >> 1, wc = wave & 1;
  f32x4 acc[4][4] = {};
  const unsigned short* Ag = Xb + (size_t)(base + m_tile * 128) * K;
  const unsigned short* Bg = W1b + ((size_t)e * FF + n0) * K;
  const int arow = lane >> 3;
  const int acolS = (((lane & 7) ^ arow) * 8);   // pre-swizzled source col (T2 + rule#21)
  const int l7 = lane & 7;
  const int jb = lane >> 4;

#pragma unroll
  for (int it = 0; it < 4; ++it) {               // prologue stage -> buf0 (8 loads/wave)
    const int c = it * 4 + wave;
    const int r = c * 8 + arow;
    gload_lds16(Ag + (size_t)r * K + acolS, &As[0][c * 512]);
    gload_lds16(Bg + (size_t)r * K + acolS, &Bs[0][c * 512]);
  }

  int cur = 0;
  for (int t = 0; t < NT; ++t) {
    const int k1 = ((t + 1) & (NT - 1)) * 64;    // last iter re-stages tile 0 (dead)
#pragma unroll
    for (int it = 0; it < 4; ++it) {             // issue next tile: stays in flight
      const int c = it * 4 + wave;
      const int r = c * 8 + arow;
      gload_lds16(Ag + (size_t)r * K + k1 + acolS, &As[cur ^ 1][c * 512]);
      gload_lds16(Bg + (size_t)r * K + k1 + acolS, &Bs[cur ^ 1][c * 512]);
    }
    asm volatile("s_waitcnt vmcnt(8)" ::: "memory");  // wait CURRENT tile only
    __builtin_amdgcn_s_barrier();
    __builtin_amdgcn_sched_barrier(0);
#pragma unroll
    for (int kk = 0; kk < 64; kk += 32) {        // compute current tile
      short8 a[4], bb[4];
      const int js = (((kk >> 3) + jb) ^ l7) << 3;
#pragma unroll
      for (int i = 0; i < 4; ++i)
        a[i] = *reinterpret_cast<const short8*>(
            &As[cur][(wr * 64 + i * 16 + (lane & 15)) * 64 + js]);
#pragma unroll
      for (int j = 0; j < 4; ++j)
        bb[j] = *reinterpret_cast<const short8*>(
            &Bs[cur][(wc * 64 + j * 16 + (lane & 15)) * 64 + js]);
#pragma unroll
      for (int i = 0; i < 4; ++i)
#pragma unroll
        for (int j = 0; j < 4; ++j)
          acc[i][j] = __builtin_amdgcn_mfma_f32_16x16x32_bf16(a[i], bb[j], acc[i][j], 0, 0, 0);
    }
    __builtin_amdgcn_sched_barrier(0);
    __builtin_amdgcn_s_barrier();                // reads of buf[cur] done before overwrite
    __builtin_amdgcn_sched_barrier(0);
    cur ^= 1;
  }

  const float* b1e = b1 + (size_t)e * FF;
  const int rbase = m_tile * 128 + wr * 64 + (lane >> 4) * 4;
  const int cbase = n0 + wc * 64 + (lane & 15);
#pragma unroll
  for (int i = 0; i < 4; ++i) {
#pragma unroll
    for (int j = 0; j < 4; ++j) {
      const int col = cbase + j * 16;
      const float bias = b1e[col];
#pragma unroll
      for (int r = 0; r < 4; ++r) {
        const int lr = rbase + i * 16 + r;
        if (lr < count)
          Hb[(size_t)(base + lr) * FF + col] = f2bf(acc[i][j][r] + bias);
      }
    }
  }
}

// ---------------- LayerNorm + exact GELU, in place on Hb ----------------
__global__ __launch_bounds__(256) void ln_gelu_kernel(
    unsigned short* __restrict__ Hb, const float* __restrict__ ln_g,
    const float* __restrict__ ln_b, const int* __restrict__ offsets) {
  const int row = blockIdx.x;
  int e = 0;
#pragma unroll
  for (int i = 1; i < NE; ++i) e += (row >= offsets[i]) ? 1 : 0;
  unsigned short* h = Hb + (size_t)row * FF;
  const int tid = threadIdx.x;
  const int lane = tid & 63, wave = tid >> 6;
  float v[8];
  float sum = 0.f, sq = 0.f;
  short8 raw = *reinterpret_cast<const short8*>(h + tid * 8);
#pragma unroll
  for (int i = 0; i < 8; ++i) {
    v[i] = bf2f((unsigned short)raw[i]);
    sum += v[i]; sq += v[i] * v[i];
  }
#pragma unroll
  for (int s = 32; s; s >>= 1) { sum += __shfl_xor(sum, s); sq += __shfl_xor(sq, s); }
  __shared__ float red[8];
  if (lane == 0) { red[wave] = sum; red[wave + 4] = sq; }
  __syncthreads();
  sum = red[0] + red[1] + red[2] + red[3];
  sq  = red[4] + red[5] + red[6] + red[7];
  const float mu = sum * (1.f / FF);
  const float var = sq * (1.f / FF) - mu * mu;
  const float rstd = rsqrtf(var + 1e-5f);
  const float* ge = ln_g + (size_t)e * FF + tid * 8;
  const float* be = ln_b + (size_t)e * FF + tid * 8;
  short8 outv;
#pragma unroll
  for (int i = 0; i < 8; ++i) {
    const float t = (v[i] - mu) * rstd * ge[i] + be[i];
    const float g = 0.5f * t * (1.f + erff(t * 0.70710678118f));
    outv[i] = (short)f2bf(g);
  }
  *reinterpret_cast<short8*>(h + tid * 8) = outv;
}

// ---------------- grouped GEMM2: out[t] = (Hb @ W2e^T + b2)*se + x[t] ----------------
__global__ __launch_bounds__(256) void gemm2_kernel(
    const unsigned short* __restrict__ Hb, const unsigned short* __restrict__ W2b,
    const float* __restrict__ b2, const float* __restrict__ res_scale,
    const int* __restrict__ ctrl, const int* __restrict__ ridx,
    const float* __restrict__ x, float* __restrict__ out) {
  const int b = blockIdx.x;
  const int lid = (b & 7) * ((8 * MAXTILES) >> 3) + (b >> 3);
  const int nx = lid & 7;
  const int ti = lid >> 3;
  if (ti >= ctrl[25]) return;
  const int e = ctrl[32 + ti];
  const int m_tile = ctrl[128 + ti];
  const int base = ctrl[16 + e];
  const int count = ctrl[16 + e + 1] - base;
  const int n0 = nx * 128;
  constexpr int K = FF;
  constexpr int NT = K / 64;
  __shared__ unsigned short As[2][128 * 64];
  __shared__ unsigned short Bs[2][128 * 64];
  const int tid = threadIdx.x;
  const int wave = tid >> 6, lane = tid & 63;
  const int wr = wave >> 1, wc = wave & 1;
  f32x4 acc[4][4] = {};
  const unsigned short* Ag = Hb + (size_t)(base + m_tile * 128) * K;
  const unsigned short* Bg = W2b + ((size_t)e * DIM + n0) * K;
  const int arow = lane >> 3;
  const int acolS = (((lane & 7) ^ arow) * 8);
  const int l7 = lane & 7;
  const int jb = lane >> 4;

#pragma unroll
  for (int it = 0; it < 4; ++it) {
    const int c = it * 4 + wave;
    const int r = c * 8 + arow;
    gload_lds16(Ag + (size_t)r * K + acolS, &As[0][c * 512]);
    gload_lds16(Bg + (size_t)r * K + acolS, &Bs[0][c * 512]);
  }

  int cur = 0;
  for (int t = 0; t < NT; ++t) {
    const int k1 = ((t + 1) & (NT - 1)) * 64;
#pragma unroll
    for (int it = 0; it < 4; ++it) {
      const int c = it * 4 + wave;
      const int r = c * 8 + arow;
      gload_lds16(Ag + (size_t)r * K + k1 + acolS, &As[cur ^ 1][c * 512]);
      gload_lds16(Bg + (size_t)r * K + k1 + acolS, &Bs[cur ^ 1][c * 512]);
    }
    asm volatile("s_waitcnt vmcnt(8)" ::: "memory");
    __builtin_amdgcn_s_barrier();
    __builtin_amdgcn_sched_barrier(0);
#pragma unroll
    for (int kk = 0; kk < 64; kk += 32) {
      short8 a[4], bb[4];
      const int js = (((kk >> 3) + jb) ^ l7) << 3;
#pragma unroll
      for (int i = 0; i < 4; ++i)
        a[i] = *reinterpret_cast<const short8*>(
            &As[cur][(wr * 64 + i * 16 + (lane & 15)) * 64 + js]);
#pragma unroll
      for (int j = 0; j < 4; ++j)
        bb[j] = *reinterpret_cast<const short8*>(
            &Bs[cur][(wc * 64 + j * 16 + (lane & 15)) * 64 + js]);
#pragma unroll
      for (int i = 0; i < 4; ++i)
#pragma unroll
        for (int j = 0; j < 4; ++j)
          acc[i][j] = __builtin_amdgcn_mfma_f32_16x16x32_bf16(a[i], bb[j], acc[i][j], 0, 0, 0);
    }
    __builtin_amdgcn_sched_barrier(0);
    __builtin_amdgcn_s_barrier();
    __builtin_amdgcn_sched_barrier(0);
    cur ^= 1;
  }

  const float* b2e = b2 + (size_t)e * DIM;
  const float se = res_scale[e];
  const int rbase = m_tile * 128 + wr * 64 + (lane >> 4) * 4;
  const int cbase = n0 + wc * 64 + (lane & 15);
#pragma unroll
  for (int i = 0; i < 4; ++i) {
#pragma unroll
    for (int r = 0; r < 4; ++r) {
      const int lr = rbase + i * 16 + r;
      if (lr < count) {
        const int trow = ridx[base + lr];
        const float* xrow = x + (size_t)trow * DIM;
        float* orow = out + (size_t)trow * DIM;
#pragma unroll
        for (int j = 0; j < 4; ++j) {
          const int col = cbase + j * 16;
          orow[col] = (acc[i][j][r] + b2e[col]) * se + xrow[col];
        }
      }
    }
  }
}

extern "C" void kernel_launch(void* const* d_in, const int* in_sizes, int n_in,
                              void* d_out, int out_size, void* d_ws, size_t ws_size,
                              hipStream_t stream) {
  const float* x         = (const float*)d_in[0];
  const float* Wg        = (const float*)d_in[1];
  const float* bg        = (const float*)d_in[2];
  const float* W1        = (const float*)d_in[3];
  const float* b1        = (const float*)d_in[4];
  const float* ln_g      = (const float*)d_in[5];
  const float* ln_b      = (const float*)d_in[6];
  const float* W2        = (const float*)d_in[7];
  const float* b2        = (const float*)d_in[8];
  const float* res_scale = (const float*)d_in[9];
  float* out = (float*)d_out;

  char* ws = (char*)d_ws;
  unsigned short* W1b = (unsigned short*)(ws);
  unsigned short* W2b = (unsigned short*)(ws + 33554432);
  unsigned short* Xb  = (unsigned short*)(ws + 67108864);
  unsigned short* Hb  = (unsigned short*)(ws + 83886080);
  int* assign  = (int*)(ws + 117964800);
  int* ridx    = (int*)(ws + 117997568);
  int* ctrl    = (int*)(ws + 118030336);
  int* rank    = (int*)(ws + 118034432);
  int* blkcnt  = (int*)(ws + 118067200);
  int* blkoff  = (int*)(ws + 118068224);

  gate_kernel<<<TOK / 4, 256, 0, stream>>>(x, Wg, bg, assign);
  convert_kernel<<<2048, 256, 0, stream>>>(W1, W1b, NE * FF * DIM);
  convert_kernel<<<2048, 256, 0, stream>>>(W2, W2b, NE * DIM * FF);
  count_rank_kernel<<<NBLK, 256, 0, stream>>>(assign, rank, blkcnt);
  scan2_kernel<<<1, 64, 0, stream>>>(ctrl, blkcnt, blkoff);
  gather_kernel<<<TOK, 256, 0, stream>>>(x, assign, rank, blkoff, ridx, Xb);
  gemm1_kernel<<<16 * MAXTILES, 256, 0, stream>>>(Xb, W1b, b1, ctrl, Hb);
  ln_gelu_kernel<<<TOK, 256, 0, stream>>>(Hb, ln_g, ln_b, ctrl + 16);
  gemm2_kernel<<<8 * MAXTILES, 256, 0, stream>>>(Hb, W2b, b2, res_scale, ctrl, ridx, x, out);
}